// Round 24
// baseline (51.699 us; speedup 1.0000x reference)
//
#include <hip/hip_runtime.h>

// Problem constants (from reference setup_inputs)
#define BZ 4
#define H 192
#define W 640
#define PIX (H * W)            // 122880 pixels per batch
#define MAXINS 200
#define CAND 16
#define CE 36                  // ch*cw
#define CE4 9                  // float4 groups per pixel
#define BATCH_FLOATS (MAXINS * CE)          // 7200 floats per batch
#define BATCH_F4     (BATCH_FLOATS / 4)     // 1800 float4 per batch
#define COMP_FLOATS (BZ * BATCH_FLOATS)     // 28800 floats
#define COMP_BYTES  (COMP_FLOATS * 4)       // 115200 bytes
#define BPB 192                             // blocks per batch
#define NBLK (BZ * BPB)                     // 768 compress blocks
#define STRIPE (PIX / BPB)                  // 640 contiguous pixels per block
#define TPB 512                             // threads per block
#define ITEMS 4                             // items per thread (item-major)
#define PARTBF_BYTES ((size_t)NBLK * BATCH_F4 * 8)   // 11.1 MB (bf16x4/item)

// bf16 pack/unpack (RNE)
__device__ __forceinline__ unsigned short f2bf(float f) {
    unsigned u = __float_as_uint(f);
    unsigned r = (u + 0x7FFFu + ((u >> 16) & 1u)) >> 16;
    return (unsigned short)r;
}
__device__ __forceinline__ float bf2f(unsigned short h) {
    return __uint_as_float(((unsigned)h) << 16);
}

// ============ compress: counting sort + condition-free pipelined gather ==
// r12..r21: six gather variants all ~28-30us; r15's VGPR=40 showed the
// compiler never pipelines loads wrapped in divergent conditionals.
// This round: UNCONDITIONAL clamped loads + mask-fma (no branches in the
// load path) -> compiler free to hoist next round's loads. Partials
// stored as bf16 (halves partials traffic).

__global__ __launch_bounds__(TPB) void compress_sort_kernel(
        const int* __restrict__ inst,
        const float4* __restrict__ compsrc,
        ushort4* __restrict__ partials) {
    __shared__ unsigned char  mloc[STRIPE];
    __shared__ unsigned short sorted[STRIPE];   // pixel ids grouped by m
    __shared__ int cnt[MAXINS];
    __shared__ int off[MAXINS + 1];
    __shared__ int off_run[MAXINS];

    const int b    = blockIdx.x / BPB;
    const int blk  = blockIdx.x % BPB;
    const int tid  = threadIdx.x;
    const int pix0 = blk * STRIPE;

    if (tid < MAXINS) cnt[tid] = 0;
    __syncthreads();                             // barrier 1

    // ---- count pass ----
    for (int p = tid; p < STRIPE; p += TPB) {
        int m = inst[b * PIX + pix0 + p];        // coalesced
        mloc[p] = (unsigned char)m;
        atomicAdd(&cnt[m], 1);                   // ds_add_u32
    }
    __syncthreads();                             // barrier 2

    // ---- single-wave exclusive scan (wave 0, shfl) ----
    if (tid < 64) {
        const int lane = tid;
        int run = 0;
        #pragma unroll
        for (int c = 0; c < 4; ++c) {
            const int idx = c * 64 + lane;
            int v = (idx < MAXINS) ? cnt[idx] : 0;
            const int own = v;
            #pragma unroll
            for (int s = 1; s < 64; s <<= 1) {
                int u = __shfl_up(v, s);
                if (lane >= s) v += u;
            }
            const int excl = run + v - own;
            if (idx < MAXINS) { off[idx] = excl; off_run[idx] = excl; }
            run += __shfl(v, 63);
        }
        if (lane == 0) off[MAXINS] = STRIPE;
    }
    __syncthreads();                             // barrier 3

    // ---- scatter pixel ids into m-sorted order ----
    for (int p = tid; p < STRIPE; p += TPB) {
        int slot = atomicAdd(&off_run[mloc[p]], 1);
        sorted[slot] = (unsigned short)p;
    }
    __syncthreads();                             // barrier 4

    // ---- phase 2: condition-free item-major accumulation ----
    const float4* src = compsrc + (size_t)(b * PIX + pix0) * CE4;
    float4 acc[ITEMS];
    int base_[ITEMS], len_[ITEMS], e4_[ITEMS], idx_[ITEMS];
    int maxlen = 0;
    #pragma unroll
    for (int j = 0; j < ITEMS; ++j) {
        const int item = tid + TPB * j;
        acc[j] = make_float4(0.f, 0.f, 0.f, 0.f);
        if (item < BATCH_F4) {
            const int m  = item / CE4;
            e4_[j]   = item - m * CE4;
            base_[j] = off[m];
            len_[j]  = off[m + 1] - off[m];
            maxlen   = len_[j] > maxlen ? len_[j] : maxlen;
        } else { base_[j] = 0; len_[j] = 0; e4_[j] = 0; }
        int s0 = base_[j]; s0 = s0 < STRIPE ? s0 : STRIPE - 1;   // clamp
        idx_[j] = (int)sorted[s0];
    }
    for (int i = 0; i < maxlen; ++i) {
        float4 v[ITEMS];
        float  msk[ITEMS];
        #pragma unroll
        for (int j = 0; j < ITEMS; ++j) {        // UNCONDITIONAL loads
            msk[j] = (i < len_[j]) ? 1.f : 0.f;
            v[j] = src[(size_t)idx_[j] * CE4 + e4_[j]];
        }
        #pragma unroll
        for (int j = 0; j < ITEMS; ++j) {        // clamped prefetch i+1
            int nx = i + 1 < len_[j] ? i + 1 : (len_[j] > 0 ? len_[j] - 1 : 0);
            int sp = base_[j] + nx; sp = sp < STRIPE ? sp : STRIPE - 1;
            idx_[j] = (int)sorted[sp];
        }
        #pragma unroll
        for (int j = 0; j < ITEMS; ++j) {        // mask-fma accumulate
            acc[j].x = fmaf(v[j].x, msk[j], acc[j].x);
            acc[j].y = fmaf(v[j].y, msk[j], acc[j].y);
            acc[j].z = fmaf(v[j].z, msk[j], acc[j].z);
            acc[j].w = fmaf(v[j].w, msk[j], acc[j].w);
        }
    }

    // ---- store full partial as bf16 (every byte overwritten) ----
    ushort4* p = partials + (size_t)blockIdx.x * BATCH_F4;
    #pragma unroll
    for (int j = 0; j < ITEMS; ++j) {
        const int item = tid + TPB * j;
        if (item < BATCH_F4) {
            ushort4 w;
            w.x = f2bf(acc[j].x); w.y = f2bf(acc[j].y);
            w.z = f2bf(acc[j].z); w.w = f2bf(acc[j].w);
            p[item] = w;                          // coalesced 8B/lane
        }
    }
}

// ============ K2: reduce bf16 partials + sel gather ======================

__global__ void reduce_priv_kernel(const ushort4* __restrict__ partials,
                                   const int* __restrict__ batchidx,
                                   const float4* __restrict__ selsrc,
                                   float4* __restrict__ comp) {
    const int t = blockIdx.x * blockDim.x + threadIdx.x;   // over 7200 float4
    if (t >= COMP_FLOATS / 4) return;
    const int e4 = t % CE4;
    const int bm = t / CE4;
    const int b  = t / BATCH_F4;
    const int j  = t - b * BATCH_F4;
    const int c  = batchidx[bm];
    float4 acc = selsrc[((size_t)bm * CAND + c) * CE4 + e4];
    const ushort4* p = partials + (size_t)b * BPB * BATCH_F4 + j;
    #pragma unroll 8
    for (int s = 0; s < BPB; ++s) {
        ushort4 w = p[(size_t)s * BATCH_F4];
        acc.x += bf2f(w.x); acc.y += bf2f(w.y);
        acc.z += bf2f(w.z); acc.w += bf2f(w.w);
    }
    comp[t] = acc;
}

// ============ fallback (tiny ws): direct atomics =========================

__global__ void init_sel_kernel(const int* __restrict__ batchidx,
                                const float4* __restrict__ selsrc,
                                float4* __restrict__ comp) {
    unsigned t = blockIdx.x * blockDim.x + threadIdx.x;
    if (t >= BZ * MAXINS * CE4) return;
    unsigned e4 = t % CE4;
    unsigned bm = t / CE4;
    int c = batchidx[bm];
    comp[bm * CE4 + e4] = selsrc[(bm * CAND + (unsigned)c) * CE4 + e4];
}

__global__ void compress_direct_kernel(const int* __restrict__ inst,
                                       const float4* __restrict__ compsrc,
                                       float* __restrict__ comp) {
    const unsigned total = BZ * PIX * CE4;
    for (unsigned t = blockIdx.x * blockDim.x + threadIdx.x; t < total;
         t += gridDim.x * blockDim.x) {
        unsigned e4 = t % CE4;
        unsigned pix = t / CE4;
        unsigned b = pix / PIX;
        int m = inst[pix];
        float4 v = compsrc[t];
        float* dst = comp + ((unsigned)(b * MAXINS + m)) * CE + e4 * 4;
        atomicAdd(dst + 0, v.x);
        atomicAdd(dst + 1, v.y);
        atomicAdd(dst + 2, v.z);
        atomicAdd(dst + 3, v.w);
    }
}

// ============ K3: inflate ================================================

__global__ void inflate_kernel(const int* __restrict__ inst,
                               const float4* __restrict__ comp,
                               float4* __restrict__ out) {
    const unsigned total = BZ * PIX * CE4;
    for (unsigned t = blockIdx.x * blockDim.x + threadIdx.x; t < total;
         t += gridDim.x * blockDim.x) {
        unsigned e4 = t % CE4;
        unsigned pix = t / CE4;
        unsigned b = pix / PIX;
        int m = inst[pix];
        out[t] = comp[((unsigned)(b * MAXINS + m)) * CE4 + e4];  // L2-hot gather
    }
}

extern "C" void kernel_launch(void* const* d_in, const int* in_sizes, int n_in,
                              void* d_out, int out_size, void* d_ws, size_t ws_size,
                              hipStream_t stream) {
    const int*    inst     = (const int*)d_in[0];      // (BZ,1,H,W) int32
    const float*  compsrc  = (const float*)d_in[1];    // (BZ,H,W,6,6) f32
    const int*    batchidx = (const int*)d_in[2];      // (BZ,MAXINS) int32
    const float*  selsrc   = (const float*)d_in[3];    // (BZ,MAXINS,CAND,6,6) f32
    float*        out      = (float*)d_out;            // (BZ,H,W,6,6) f32
    float*        comp     = (float*)d_ws;             // 115.2 KB @ ws[0]

    if (ws_size >= (size_t)COMP_BYTES + PARTBF_BYTES) {
        // --- main path: counting-sort compress, bf16 partials ---
        ushort4* partials = (ushort4*)(comp + COMP_FLOATS);
        compress_sort_kernel<<<NBLK, TPB, 0, stream>>>(inst, (const float4*)compsrc,
                                                       partials);
        reduce_priv_kernel<<<(COMP_FLOATS / 4 + 255) / 256, 256, 0, stream>>>(
            partials, batchidx, (const float4*)selsrc, (float4*)comp);
    } else {
        // --- fallback: direct atomics into comp ---
        const int total = BZ * MAXINS * CE4;
        init_sel_kernel<<<(total + 255) / 256, 256, 0, stream>>>(
            batchidx, (const float4*)selsrc, (float4*)comp);
        compress_direct_kernel<<<2048, 256, 0, stream>>>(inst, (const float4*)compsrc,
                                                         comp);
    }

    // K3: inflate comp back to per-pixel output
    inflate_kernel<<<2048, 256, 0, stream>>>(inst, (const float4*)comp, (float4*)out);
}

// Round 25
// 50.072 us; speedup vs baseline: 1.0325x; 1.0325x over previous
//
#include <hip/hip_runtime.h>

// Problem constants (from reference setup_inputs)
#define BZ 4
#define H 192
#define W 640
#define PIX (H * W)            // 122880 pixels per batch
#define MAXINS 200
#define CAND 16
#define CE 36                  // ch*cw
#define CE4 9                  // float4 groups per pixel
#define BATCH_FLOATS (MAXINS * CE)          // 7200 floats per batch
#define BATCH_F4     (BATCH_FLOATS / 4)     // 1800 float4 per batch
#define COMP_FLOATS (BZ * BATCH_FLOATS)     // 28800 floats
#define COMP_BYTES  (COMP_FLOATS * 4)       // 115200 bytes
#define BPB 192                             // blocks per batch
#define NBLK (BZ * BPB)                     // 768 compress blocks
#define STRIPE (PIX / BPB)                  // 640 contiguous pixels per block
#define TPB 512                             // threads per block
#define PAD 8                               // compile-time padded segment length
#define PART_BYTES ((size_t)NBLK * BATCH_FLOATS * 4)   // 22.1 MB (fp32)

// ============ compress: counting sort + straight-line padded gather ======
// r12..r24: seven gather variants, all ~28-33us. Common machine-level cause
// (r15 VGPR=40): dynamic maxlen loop -> compiler buffers ONE round of loads
// -> rounds serialize on L2 latency (~600cyc each). This round: segments
// padded to compile-time 8 slots; 16 independent loads issued straight-line
// per pass (2 passes x 2 items). No dynamic loop -> nothing to serialize.
// Signature if right: VGPR ~90-110 and compress drops to ~15-20us.

__global__ __launch_bounds__(TPB) void compress_sort_kernel(
        const int* __restrict__ inst,
        const float4* __restrict__ compsrc,
        float4* __restrict__ partials) {
    __shared__ unsigned char  mloc[STRIPE];
    __shared__ unsigned short sorted[STRIPE];   // pixel ids grouped by m
    __shared__ int cnt[MAXINS];
    __shared__ int off[MAXINS + 1];
    __shared__ int off_run[MAXINS];

    const int b    = blockIdx.x / BPB;
    const int blk  = blockIdx.x % BPB;
    const int tid  = threadIdx.x;
    const int pix0 = blk * STRIPE;

    if (tid < MAXINS) cnt[tid] = 0;
    __syncthreads();                             // barrier 1

    // ---- count pass ----
    for (int p = tid; p < STRIPE; p += TPB) {
        int m = inst[b * PIX + pix0 + p];        // coalesced
        mloc[p] = (unsigned char)m;
        atomicAdd(&cnt[m], 1);                   // ds_add_u32
    }
    __syncthreads();                             // barrier 2

    // ---- single-wave exclusive scan (wave 0, shfl) ----
    if (tid < 64) {
        const int lane = tid;
        int run = 0;
        #pragma unroll
        for (int c = 0; c < 4; ++c) {
            const int idx = c * 64 + lane;
            int v = (idx < MAXINS) ? cnt[idx] : 0;
            const int own = v;
            #pragma unroll
            for (int s = 1; s < 64; s <<= 1) {
                int u = __shfl_up(v, s);
                if (lane >= s) v += u;
            }
            const int excl = run + v - own;
            if (idx < MAXINS) { off[idx] = excl; off_run[idx] = excl; }
            run += __shfl(v, 63);
        }
        if (lane == 0) off[MAXINS] = STRIPE;
    }
    __syncthreads();                             // barrier 3

    // ---- scatter pixel ids into m-sorted order ----
    for (int p = tid; p < STRIPE; p += TPB) {
        int slot = atomicAdd(&off_run[mloc[p]], 1);
        sorted[slot] = (unsigned short)p;
    }
    __syncthreads();                             // barrier 4

    // ---- phase 2: straight-line padded gather (2 passes x 2 items) ----
    const float4* src = compsrc + (size_t)(b * PIX + pix0) * CE4;
    float4* pout = partials + (size_t)blockIdx.x * BATCH_F4;

    #pragma unroll
    for (int pass = 0; pass < 2; ++pass) {
        int base_[2], len_[2], e4_[2];
        #pragma unroll
        for (int j = 0; j < 2; ++j) {
            const int item = tid + TPB * (2 * pass + j);
            if (item < BATCH_F4) {
                const int m = item / CE4;
                e4_[j]   = item - m * CE4;
                base_[j] = off[m];
                len_[j]  = off[m + 1] - off[m];
            } else { e4_[j] = 0; base_[j] = 0; len_[j] = 0; }
        }
        // 16 clamped LDS index reads (all independent)
        int idx_[2][PAD];
        #pragma unroll
        for (int j = 0; j < 2; ++j) {
            const int last = len_[j] > 0 ? len_[j] - 1 : 0;
            #pragma unroll
            for (int s = 0; s < PAD; ++s) {
                int ss = s < last ? s : last;
                int sp = base_[j] + ss;
                sp = sp < STRIPE ? sp : STRIPE - 1;
                idx_[j][s] = (int)sorted[sp];
            }
        }
        // 16 independent global loads, issued straight-line
        float4 v_[2][PAD];
        #pragma unroll
        for (int j = 0; j < 2; ++j)
            #pragma unroll
            for (int s = 0; s < PAD; ++s)
                v_[j][s] = src[(size_t)idx_[j][s] * CE4 + e4_[j]];
        // masked combine (loads already in flight/landed)
        float4 acc[2];
        #pragma unroll
        for (int j = 0; j < 2; ++j) {
            acc[j] = make_float4(0.f, 0.f, 0.f, 0.f);
            #pragma unroll
            for (int s = 0; s < PAD; ++s)
                if (s < len_[j]) {
                    acc[j].x += v_[j][s].x; acc[j].y += v_[j][s].y;
                    acc[j].z += v_[j][s].z; acc[j].w += v_[j][s].w;
                }
        }
        // rare tail (len > PAD): ~0.6% of items
        #pragma unroll
        for (int j = 0; j < 2; ++j)
            for (int i = PAD; i < len_[j]; ++i) {
                float4 v = src[(size_t)sorted[base_[j] + i] * CE4 + e4_[j]];
                acc[j].x += v.x; acc[j].y += v.y;
                acc[j].z += v.z; acc[j].w += v.w;
            }
        // coalesced store of this pass's items
        #pragma unroll
        for (int j = 0; j < 2; ++j) {
            const int item = tid + TPB * (2 * pass + j);
            if (item < BATCH_F4) pout[item] = acc[j];
        }
    }
}

// ============ K2: reduce partials + sel gather ===========================

__global__ void reduce_priv_kernel(const float4* __restrict__ partials,
                                   const int* __restrict__ batchidx,
                                   const float4* __restrict__ selsrc,
                                   float4* __restrict__ comp) {
    const int t = blockIdx.x * blockDim.x + threadIdx.x;   // over 7200 float4
    if (t >= COMP_FLOATS / 4) return;
    const int e4 = t % CE4;
    const int bm = t / CE4;
    const int b  = t / BATCH_F4;
    const int j  = t - b * BATCH_F4;
    const int c  = batchidx[bm];
    float4 acc = selsrc[((size_t)bm * CAND + c) * CE4 + e4];
    const float4* p = partials + (size_t)b * BPB * BATCH_F4 + j;
    #pragma unroll 8
    for (int s = 0; s < BPB; ++s) {
        float4 v = p[(size_t)s * BATCH_F4];
        acc.x += v.x; acc.y += v.y; acc.z += v.z; acc.w += v.w;
    }
    comp[t] = acc;
}

// ============ fallback (tiny ws): direct atomics =========================

__global__ void init_sel_kernel(const int* __restrict__ batchidx,
                                const float4* __restrict__ selsrc,
                                float4* __restrict__ comp) {
    unsigned t = blockIdx.x * blockDim.x + threadIdx.x;
    if (t >= BZ * MAXINS * CE4) return;
    unsigned e4 = t % CE4;
    unsigned bm = t / CE4;
    int c = batchidx[bm];
    comp[bm * CE4 + e4] = selsrc[(bm * CAND + (unsigned)c) * CE4 + e4];
}

__global__ void compress_direct_kernel(const int* __restrict__ inst,
                                       const float4* __restrict__ compsrc,
                                       float* __restrict__ comp) {
    const unsigned total = BZ * PIX * CE4;
    for (unsigned t = blockIdx.x * blockDim.x + threadIdx.x; t < total;
         t += gridDim.x * blockDim.x) {
        unsigned e4 = t % CE4;
        unsigned pix = t / CE4;
        unsigned b = pix / PIX;
        int m = inst[pix];
        float4 v = compsrc[t];
        float* dst = comp + ((unsigned)(b * MAXINS + m)) * CE + e4 * 4;
        atomicAdd(dst + 0, v.x);
        atomicAdd(dst + 1, v.y);
        atomicAdd(dst + 2, v.z);
        atomicAdd(dst + 3, v.w);
    }
}

// ============ K3: inflate ================================================

__global__ void inflate_kernel(const int* __restrict__ inst,
                               const float4* __restrict__ comp,
                               float4* __restrict__ out) {
    const unsigned total = BZ * PIX * CE4;
    for (unsigned t = blockIdx.x * blockDim.x + threadIdx.x; t < total;
         t += gridDim.x * blockDim.x) {
        unsigned e4 = t % CE4;
        unsigned pix = t / CE4;
        unsigned b = pix / PIX;
        int m = inst[pix];
        out[t] = comp[((unsigned)(b * MAXINS + m)) * CE4 + e4];  // L2-hot gather
    }
}

extern "C" void kernel_launch(void* const* d_in, const int* in_sizes, int n_in,
                              void* d_out, int out_size, void* d_ws, size_t ws_size,
                              hipStream_t stream) {
    const int*    inst     = (const int*)d_in[0];      // (BZ,1,H,W) int32
    const float*  compsrc  = (const float*)d_in[1];    // (BZ,H,W,6,6) f32
    const int*    batchidx = (const int*)d_in[2];      // (BZ,MAXINS) int32
    const float*  selsrc   = (const float*)d_in[3];    // (BZ,MAXINS,CAND,6,6) f32
    float*        out      = (float*)d_out;            // (BZ,H,W,6,6) f32
    float*        comp     = (float*)d_ws;             // 115.2 KB @ ws[0]

    if (ws_size >= (size_t)COMP_BYTES + PART_BYTES) {
        // --- main path: counting-sort compress, straight-line gather ---
        float4* partials = (float4*)(comp + COMP_FLOATS);
        compress_sort_kernel<<<NBLK, TPB, 0, stream>>>(inst, (const float4*)compsrc,
                                                       partials);
        reduce_priv_kernel<<<(COMP_FLOATS / 4 + 255) / 256, 256, 0, stream>>>(
            partials, batchidx, (const float4*)selsrc, (float4*)comp);
    } else {
        // --- fallback: direct atomics into comp ---
        const int total = BZ * MAXINS * CE4;
        init_sel_kernel<<<(total + 255) / 256, 256, 0, stream>>>(
            batchidx, (const float4*)selsrc, (float4*)comp);
        compress_direct_kernel<<<2048, 256, 0, stream>>>(inst, (const float4*)compsrc,
                                                         comp);
    }

    // K3: inflate comp back to per-pixel output
    inflate_kernel<<<2048, 256, 0, stream>>>(inst, (const float4*)comp, (float4*)out);
}